// Round 4
// baseline (271.313 us; speedup 1.0000x reference)
//
#include <hip/hip_runtime.h>
#include <hip/hip_bf16.h>
#include <hip/hip_fp8.h>

#define FEAT    256
#define KDIM    512   // FEAT + EMBED
#define EMBED   256
#define BATCH   50000
#define NSAMP   25
#define N_NODES 100000
#define NAN_FILL 0.01f

#define NTILE   32    // batch items per block -> LDS 33.3KB -> 4 blocks/CU (16 waves)
#define ITEMS   (NTILE / 4)   // items per wave
#define LSTRIDE 520   // shorts per LDS row: 512 + 8 pad -> 260 words == 4 (mod 32)
                      // => B-frag ds_read_b128 start-bank = 4*(r+q): perfect 8-cycle tiling

typedef __attribute__((ext_vector_type(8))) short  short8;
typedef __attribute__((ext_vector_type(4))) float  floatx4;
typedef __attribute__((ext_vector_type(2))) float  float2v;
typedef __attribute__((ext_vector_type(4))) unsigned short ushort4v;
typedef __attribute__((ext_vector_type(4))) float  float4v;

#if __has_builtin(__builtin_amdgcn_cvt_pk_f32_fp8)
#define PK_FP8_DEC 1
#else
#define PK_FP8_DEC 0
#endif
#if __has_builtin(__builtin_amdgcn_cvt_pk_fp8_f32)
#define PK_FP8_ENC 1
#else
#define PK_FP8_ENC 0
#endif

__device__ inline unsigned short f2bf(float x) {
    __hip_bfloat16 h = __float2bfloat16(x);
    union { __hip_bfloat16 h; unsigned short u; } c; c.h = h;
    return c.u;
}
__device__ inline unsigned char f2fp8(float x) {
    __hip_fp8_e4m3 t(x);
    return (unsigned char)t.__x;
}
__device__ inline float fp8f(unsigned v) {
    __hip_fp8_e4m3 t; t.__x = (unsigned char)v;
    return (float)t;
}

// ---------------- Stage 0: features f32 -> fp8 e4m3 table (25.6 MB) ----------------
__global__ __launch_bounds__(256) void fconv8_kernel(
    const float* __restrict__ F, unsigned char* __restrict__ F8)
{
    const size_t i = ((size_t)blockIdx.x * 256 + threadIdx.x) * 8;
    float4v a = *(const float4v*)(F + i);
    float4v b = *(const float4v*)(F + i + 4);
#if PK_FP8_ENC
    unsigned w0 = (unsigned)__builtin_amdgcn_cvt_pk_fp8_f32(a[0], a[1], 0, false);
    w0 = (unsigned)__builtin_amdgcn_cvt_pk_fp8_f32(a[2], a[3], (int)w0, true);
    unsigned w1 = (unsigned)__builtin_amdgcn_cvt_pk_fp8_f32(b[0], b[1], 0, false);
    w1 = (unsigned)__builtin_amdgcn_cvt_pk_fp8_f32(b[2], b[3], (int)w1, true);
    uint2 o; o.x = w0; o.y = w1;
    *(uint2*)(F8 + i) = o;
#else
    union { unsigned char c[8]; uint2 v; } o;
    o.c[0] = f2fp8(a[0]); o.c[1] = f2fp8(a[1]); o.c[2] = f2fp8(a[2]); o.c[3] = f2fp8(a[3]);
    o.c[4] = f2fp8(b[0]); o.c[5] = f2fp8(b[1]); o.c[6] = f2fp8(b[2]); o.c[7] = f2fp8(b[3]);
    *(uint2*)(F8 + i) = o.v;
#endif
}

// ---------------- Stage 0b: W f32 -> bf16 ----------------
__global__ __launch_bounds__(256) void wconv_kernel(
    const float* __restrict__ W, unsigned short* __restrict__ Wb)
{
    const int i = blockIdx.x * 256 + threadIdx.x;   // grid sized exactly 256*512
    Wb[i] = f2bf(W[i]);
}

// ---------------- Fused: gather+mean -> LDS tile -> MFMA GEMM -> ReLU -> out ----------
// Block: 256 threads (4 waves), NTILE=32 -> LDS 33.3KB -> 4 blocks/CU (16 waves/CU).
// Round 0-2 lesson: the bottleneck is the per-item SERIAL chain
//   s_load idx -> wait -> issue gathers -> wait -> convert
// (two exposed round-trips per item; invariant across occupancy changes).
// Round 3/4: explicit 2-stage software pipeline across items, A/B register-renamed,
// sched_barrier(0) fences so the scheduler cannot re-serialize. Outer loop is
// NOT unrolled (code-size hazard, r3 infra failure suspect); all per-sample
// arrays are statically indexed inside their own fully-unrolled inner loops.
// Phase 2: out[e,b] = relu(sum_k W[e,k]*C[b,k]); M=256 (wave covers 64 rows),
//          N=32 (2 x 16-col tiles), K=512. A from global (L2-resident W), B from LDS.
// MFMA 16x16x32 bf16 layouts (guide-verified):
//   A: lane holds A[m=lane&15][k=(lane>>4)*8+j]; B: B[k=(lane>>4)*8+j][n=lane&15]
//   D: row=(lane>>4)*4+reg, col=lane&15
__global__ __launch_bounds__(256, 4) void enc_kernel(
    const float* __restrict__ F,            // [N_NODES, 256] f32
    const unsigned char* __restrict__ F8,   // [N_NODES, 256] fp8
    const unsigned short* __restrict__ Wb,  // [256, 512] bf16
    const int* __restrict__ nodes,
    const int* __restrict__ neigh,          // [BATCH, NSAMP]
    float* __restrict__ out)                // [256, BATCH] f32
{
    __shared__ unsigned short cl[NTILE * LSTRIDE];  // 33,280 B -> 4 blocks/CU

    const int lane = threadIdx.x & 63;
    const int wave = threadIdx.x >> 6;
    const int q = lane >> 4;
    const int r = lane & 15;
    const int nbase = blockIdx.x * NTILE;

    // ---- Phase 1: software-pipelined gather + mean into LDS ----
    {
        int nodeA, nodeB;
        int idxA[NSAMP], idxB[NSAMP];
        float4v svA, svB;
        unsigned wvA[NSAMP], wvB[NSAMP];

#define LOADIDX(S, IT) do {                                                   \
        int b_ = nbase + wave * ITEMS + (IT);                                 \
        if (b_ >= BATCH) b_ = BATCH - 1;                                      \
        node##S = nodes[b_];                                                  \
        const int* nb_ = neigh + (size_t)b_ * NSAMP;                          \
        _Pragma("unroll")                                                     \
        for (int j_ = 0; j_ < NSAMP; ++j_) idx##S[j_] = nb_[j_];              \
    } while (0)

#define GATHER(S) do {                                                        \
        sv##S = *(const float4v*)(F + (size_t)node##S * FEAT + lane * 4);     \
        _Pragma("unroll")                                                     \
        for (int j_ = 0; j_ < NSAMP; ++j_)                                    \
            wv##S[j_] = *(const unsigned*)(F8 + (size_t)idx##S[j_] * FEAT + lane * 4); \
    } while (0)

#if PK_FP8_DEC
#define ACCUM(S, J) do {                                                      \
        s01 += __builtin_amdgcn_cvt_pk_f32_fp8((int)wv##S[J], false);         \
        s23 += __builtin_amdgcn_cvt_pk_f32_fp8((int)wv##S[J], true);          \
    } while (0)
#else
#define ACCUM(S, J) do {                                                      \
        s01[0] += fp8f(wv##S[J]);       s01[1] += fp8f(wv##S[J] >> 8);        \
        s23[0] += fp8f(wv##S[J] >> 16); s23[1] += fp8f(wv##S[J] >> 24);       \
    } while (0)
#endif

#define CONSUME(S, IT) do {                                                   \
        float2v s01 = {0.f, 0.f}, s23 = {0.f, 0.f};                           \
        _Pragma("unroll")                                                     \
        for (int j_ = 0; j_ < NSAMP; ++j_) ACCUM(S, j_);                      \
        const float inv_ = 1.0f / NSAMP;                                      \
        float m0 = s01[0] * inv_, m1 = s01[1] * inv_;                         \
        float m2 = s23[0] * inv_, m3 = s23[1] * inv_;                         \
        if (m0 != m0) m0 = NAN_FILL;                                          \
        if (m1 != m1) m1 = NAN_FILL;                                          \
        if (m2 != m2) m2 = NAN_FILL;                                          \
        if (m3 != m3) m3 = NAN_FILL;                                          \
        unsigned short* row_ = cl + (wave * ITEMS + (IT)) * LSTRIDE;          \
        ushort4v s_;                                                          \
        s_[0] = f2bf(sv##S[0]); s_[1] = f2bf(sv##S[1]);                       \
        s_[2] = f2bf(sv##S[2]); s_[3] = f2bf(sv##S[3]);                       \
        *(ushort4v*)(row_ + lane * 4) = s_;                                   \
        ushort4v m_;                                                          \
        m_[0] = f2bf(m0); m_[1] = f2bf(m1); m_[2] = f2bf(m2); m_[3] = f2bf(m3); \
        *(ushort4v*)(row_ + FEAT + lane * 4) = m_;                            \
    } while (0)

        // prologue: indices for items 0,1; gathers for item 0 in flight
        LOADIDX(A, 0);
        LOADIDX(B, 1);
        GATHER(A);

        #pragma unroll 1
        for (int it = 0; it < ITEMS; it += 2) {
            GATHER(B);                                // issue item it+1 gathers
            if (it + 2 < ITEMS) LOADIDX(A, it + 2);   // prefetch indices it+2
            __builtin_amdgcn_sched_barrier(0);        // pin: loads above, consume below
            CONSUME(A, it);                           // item it (loads issued 1 stage ago)
            if (it + 2 < ITEMS) GATHER(A);            // issue item it+2 gathers
            if (it + 3 < ITEMS) LOADIDX(B, it + 3);   // prefetch indices it+3
            __builtin_amdgcn_sched_barrier(0);
            CONSUME(B, it + 1);                       // item it+1
        }
#undef LOADIDX
#undef GATHER
#undef ACCUM
#undef CONSUME
    }
    __syncthreads();

    // ---- Phase 2: MFMA GEMM from LDS tile ----
    const int mbase = wave * 64;                    // 4 waves x 64 rows = 256
    const short* Wp = (const short*)Wb;
    const short* cp = (const short*)cl;

    floatx4 acc[4][2] = {};

    for (int k = 0; k < KDIM; k += 32) {
        short8 afr[4], bfr[2];
        #pragma unroll
        for (int mt = 0; mt < 4; ++mt) {
            const short* p = Wp + (size_t)(mbase + mt * 16 + r) * KDIM + k + q * 8;
            afr[mt] = *(const short8*)p;
        }
        #pragma unroll
        for (int nt = 0; nt < 2; ++nt) {
            const short* p = cp + (nt * 16 + r) * LSTRIDE + k + q * 8;
            bfr[nt] = *(const short8*)p;
        }
        #pragma unroll
        for (int mt = 0; mt < 4; ++mt)
            #pragma unroll
            for (int nt = 0; nt < 2; ++nt)
                acc[mt][nt] = __builtin_amdgcn_mfma_f32_16x16x32_bf16(
                    afr[mt], bfr[nt], acc[mt][nt], 0, 0, 0);
    }

    // ---- Epilogue: ReLU + store ----
    #pragma unroll
    for (int mt = 0; mt < 4; ++mt) {
        #pragma unroll
        for (int nt = 0; nt < 2; ++nt) {
            const int col = nbase + nt * 16 + r;
            if (col < BATCH) {
                #pragma unroll
                for (int i = 0; i < 4; ++i) {
                    const int row = mbase + mt * 16 + q * 4 + i;
                    float v = acc[mt][nt][i];
                    out[(size_t)row * BATCH + col] = v > 0.f ? v : 0.f;
                }
            }
        }
    }
}

extern "C" void kernel_launch(void* const* d_in, const int* in_sizes, int n_in,
                              void* d_out, int out_size, void* d_ws, size_t ws_size,
                              hipStream_t stream) {
    const float* features = (const float*)d_in[0];   // [100000, 256] f32
    const float* weight   = (const float*)d_in[1];   // [256, 512] f32
    const int*   nodes    = (const int*)d_in[2];     // [50000]
    const int*   neigh    = (const int*)d_in[3];     // [50000, 25]
    float* out = (float*)d_out;                      // [256, 50000] f32

    unsigned char* F8  = (unsigned char*)d_ws;                         // 25.6 MB
    unsigned short* Wb = (unsigned short*)(F8 + (size_t)N_NODES * FEAT); // +0.25 MB

    fconv8_kernel<<<(N_NODES * FEAT) / (256 * 8), 256, 0, stream>>>(features, F8);
    wconv_kernel<<<(EMBED * KDIM) / 256, 256, 0, stream>>>(weight, Wb);

    const int nblocks = (BATCH + NTILE - 1) / NTILE;  // 1563
    enc_kernel<<<nblocks, 256, 0, stream>>>(features, F8, Wb, nodes, neigh, out);
}